// Round 6
// baseline (320.575 us; speedup 1.0000x reference)
//
#include <hip/hip_runtime.h>
#include <hip/hip_bf16.h>

#define DEV __device__ __forceinline__

typedef __attribute__((ext_vector_type(4))) float f32x4;
typedef __attribute__((ext_vector_type(16))) float f32x16;
typedef __attribute__((ext_vector_type(8))) __bf16 bf16x8;
typedef __attribute__((ext_vector_type(8))) unsigned short ushort8;
typedef __attribute__((ext_vector_type(4))) unsigned int uint32x4;

static constexpr int BATCH = 2, SEQ = 2048, DM = 1024, NH = 16, HDIM = 64;
static constexpr size_t XSZ = (size_t)BATCH * SEQ * DM;  // 4194304 elems per [4096,1024]

DEV unsigned short f2bf(float f) {
  union { float f; unsigned int u; } v; v.f = f;
  unsigned int r = (v.u + 0x7fffu + ((v.u >> 16) & 1u)) >> 16;  // RNE; inputs are finite
  return (unsigned short)r;
}

DEV bf16x8 ld8(const unsigned short* p) {
  return __builtin_bit_cast(bf16x8, *(const ushort8*)p);
}

DEV f32x4 mfma16(bf16x8 a, bf16x8 b, f32x4 c) {
  return __builtin_amdgcn_mfma_f32_16x16x32_bf16(a, b, c, 0, 0, 0);
}
DEV f32x16 mfma32(bf16x8 a, bf16x8 b, f32x16 c) {
  return __builtin_amdgcn_mfma_f32_32x32x16_bf16(a, b, c, 0, 0, 0);
}

DEV unsigned cvtpk(float lo, float hi) {  // D[15:0]=bf16(lo), D[31:16]=bf16(hi)
  unsigned r;
  asm("v_cvt_pk_bf16_f32 %0, %1, %2" : "=v"(r) : "v"(lo), "v"(hi));
  return r;
}
DEV void plswap(unsigned& a, unsigned& b) {  // swap a.hi-lanes <-> b.lo-lanes
  asm("v_permlane32_swap_b32 %0, %1" : "+v"(a), "+v"(b));
}

// async global->LDS, 16B per lane; lds dest is wave-uniform base + lane*16
DEV void gll16(const unsigned short* g, unsigned short* l) {
  __builtin_amdgcn_global_load_lds(
      (__attribute__((address_space(1))) void*)(unsigned short*)g,
      (__attribute__((address_space(3))) void*)l, 16, 0, 0);
}

// ---------------------------------------------------------------- converts
__global__ __launch_bounds__(256)
void k_convert_x(const float* __restrict__ vis, const float* __restrict__ inff,
                 unsigned short* __restrict__ out) {
  const float* src = blockIdx.z ? inff : vis;
  unsigned short* dst = out + (size_t)blockIdx.z * XSZ;
  const size_t i = ((size_t)blockIdx.x * 256 + threadIdx.x) * 8;
  const float4 a = *(const float4*)(src + i);
  const float4 b = *(const float4*)(src + i + 4);
  ushort8 v;
  v[0] = f2bf(a.x); v[1] = f2bf(a.y); v[2] = f2bf(a.z); v[3] = f2bf(a.w);
  v[4] = f2bf(b.x); v[5] = f2bf(b.y); v[6] = f2bf(b.z); v[7] = f2bf(b.w);
  *(ushort8*)(dst + i) = v;
}

struct WPtrs { const float* w[8]; };

// W fp32 [K=1024][N=1024] row-major  ->  Wt bf16 [N][K] row-major
__global__ __launch_bounds__(256)
void k_convert_w(WPtrs p, unsigned short* __restrict__ wt) {
  const float* W = p.w[blockIdx.z];
  unsigned short* Wt = wt + (size_t)blockIdx.z * (1024 * 1024);
  const int k0 = blockIdx.y * 64, n0 = blockIdx.x * 64;
  __shared__ unsigned short t[64][68];
  const int tx = threadIdx.x & 15, ty = threadIdx.x >> 4;
#pragma unroll
  for (int i = 0; i < 4; ++i) {
    const int kr = ty * 4 + i;
    const float4 v = *(const float4*)(W + (size_t)(k0 + kr) * 1024 + n0 + tx * 4);
    t[kr][tx * 4 + 0] = f2bf(v.x); t[kr][tx * 4 + 1] = f2bf(v.y);
    t[kr][tx * 4 + 2] = f2bf(v.z); t[kr][tx * 4 + 3] = f2bf(v.w);
  }
  __syncthreads();
#pragma unroll
  for (int i = 0; i < 4; ++i) {
    const int nr = ty * 4 + i;
    ushort4 o;
    o.x = t[tx * 4 + 0][nr]; o.y = t[tx * 4 + 1][nr];
    o.z = t[tx * 4 + 2][nr]; o.w = t[tx * 4 + 3][nr];
    *(ushort4*)(Wt + (size_t)(n0 + nr) * 1024 + k0 + tx * 4) = o;
  }
}

// ---------------------------------------------------------------- GEMM 256x256, 8-phase
// C[4096,1024] = A[4096,1024](bf16) @ Wt[1024(n),1024(k)]^T(bf16) + bias
// 512 thr = 8 waves (2M x 4N), per-wave 128x64 out, BK=64, dbuf LDS 128KB.
// Phase p of K-tile t: {ds_read frags || stage 1 half-tile -> barrier ->
// lgkmcnt(0) -> 16 MFMA -> barrier}; counted vmcnt(4) at tile boundary only.
// Staging ledger: A-halves of t+1 at p0/p1 (slots died at (t-1).p3),
// B-halves of t+2 at p2/p3 (slots died at t.p0). Boundary vmcnt(4) leaves
// exactly B(t+2)'s 4 loads in flight. Prologue: tile0 + B(1), vmcnt(4).
// mode 0: bf16 heads [B,H,S,HD] (value*scale); mode 2: [B,H,HD,S]; mode 1: fp32.
struct GemmJob { const unsigned short* A; const unsigned short* W;
                 const float* bias; void* out; float scale; int mode; };
struct GemmJobs { GemmJob j[6]; };

__global__ __launch_bounds__(512, 2)
void k_gemm256(GemmJobs jobs) {
  const int lane = threadIdx.x & 63, w = threadIdx.x >> 6;   // w 0..7
  const int wr = w >> 2, wc = w & 3;                         // 2x4 wave grid
  const int r = lane & 15, g = lane >> 4;

  // XCD-chunked bijective swizzle: lin = bx + 4*by + 64*bz; chunk = tot/8.
  const int lin = blockIdx.x + (blockIdx.y << 2) + ((blockIdx.z * 16) << 2);
  const int q = gridDim.z << 3;                              // (64*gz)/8
  const int swz = (lin & 7) * q + (lin >> 3);
  const int bxs = swz & 3, bys = (swz >> 2) & 15, bzs = swz >> 6;
  const GemmJob jb = jobs.j[bzs];
  const int bm = bys * 256, bn = bxs * 256;

  // [dbuf][A=0/B=1][half][128 rows x 64 k] = 128 KB
  __shared__ __align__(16) unsigned short L[2][2][2][8192];

  const int uu = ((lane & 7) ^ (lane >> 3)) * 8;             // pre-swizzled src chunk
  const int rb = w * 8 + (lane >> 3);                        // staging row within 64-grp

  auto stage = [&](int d_, int ab, int h, int tt) {
#pragma unroll
    for (int j = 0; j < 2; ++j) {
      const int R = h * 128 + j * 64 + rb;
      const unsigned short* src = (ab ? jb.W : jb.A)
          + (size_t)((ab ? bn : bm) + R) * DM + tt * 64 + uu;
      gll16(src, &L[d_][ab][h][(j * 8 + w) * 512]);
    }
  };

  f32x4 acc[8][4] = {};
  constexpr int NKT = DM / 64;  // 16

  // prologue: tile0 (A0,A1,B0,B1) + tile1's B halves; wait oldest 8 (=tile0)
  stage(0, 0, 0, 0); stage(0, 0, 1, 0); stage(0, 1, 0, 0); stage(0, 1, 1, 0);
  stage(1, 1, 0, 1); stage(1, 1, 1, 1);
  asm volatile("s_waitcnt vmcnt(4)" ::: "memory");
  __builtin_amdgcn_s_barrier();
  __builtin_amdgcn_sched_barrier(0);

  const int px0 = (g ^ (r & 7)) * 8, px1 = ((4 + g) ^ (r & 7)) * 8;

  for (int t = 0; t < NKT; ++t) {
    const int d = t & 1;
    const unsigned short* Ab = &L[d][0][wr][0];
    const unsigned short* Bb = &L[d][1][wc >> 1][0];
    bf16x8 bfr[4][2];

#pragma unroll
    for (int p = 0; p < 4; ++p) {
      if (p == 0) {
#pragma unroll
        for (int n = 0; n < 4; ++n) {
          const int rowl = (wc & 1) * 64 + n * 16 + r;
          bfr[n][0] = ld8(Bb + rowl * 64 + px0);
          bfr[n][1] = ld8(Bb + rowl * 64 + px1);
        }
      }
      bf16x8 af[2][2];
#pragma unroll
      for (int m2 = 0; m2 < 2; ++m2) {
        const int rowl = (2 * p + m2) * 16 + r;
        af[m2][0] = ld8(Ab + rowl * 64 + px0);
        af[m2][1] = ld8(Ab + rowl * 64 + px1);
      }
      // stage one half-tile (targets slots proven dead; see ledger above)
      if (p == 0 && t + 1 < NKT) stage(d ^ 1, 0, 0, t + 1);
      if (p == 1 && t + 1 < NKT) stage(d ^ 1, 0, 1, t + 1);
      if (p == 2 && t + 2 < NKT) stage(d, 1, 0, t + 2);
      if (p == 3 && t + 2 < NKT) stage(d, 1, 1, t + 2);

      __builtin_amdgcn_s_barrier();                    // barrier A
      asm volatile("s_waitcnt lgkmcnt(0)" ::: "memory");
      __builtin_amdgcn_sched_barrier(0);

      __builtin_amdgcn_s_setprio(1);
#pragma unroll
      for (int m2 = 0; m2 < 2; ++m2) {
        const int mm = 2 * p + m2;
#pragma unroll
        for (int n = 0; n < 4; ++n) {
          acc[mm][n] = mfma16(af[m2][0], bfr[n][0], acc[mm][n]);
          acc[mm][n] = mfma16(af[m2][1], bfr[n][1], acc[mm][n]);
        }
      }
      __builtin_amdgcn_s_setprio(0);

      if (p < 3) {
        __builtin_amdgcn_s_barrier();                  // barrier B
      } else if (t + 1 < NKT) {
        // tile boundary: wait for (t+1)'s A-halves; keep B(t+2) in flight
        if (t + 2 < NKT) asm volatile("s_waitcnt vmcnt(4)" ::: "memory");
        else             asm volatile("s_waitcnt vmcnt(0)" ::: "memory");
        __builtin_amdgcn_s_barrier();                  // barrier B (boundary)
        __builtin_amdgcn_sched_barrier(0);
      }
    }
  }

  // epilogue; C/D frag: row = 4*g + i, col = r (m89-verified)
  if (jb.mode == 0) {
    unsigned short* O = (unsigned short*)jb.out;
#pragma unroll
    for (int n = 0; n < 4; ++n) {
      const int nc = bn + wc * 64 + n * 16 + r;
      const float bv = jb.bias[nc];
      const int h = nc >> 6, hd = nc & 63;
#pragma unroll
      for (int m = 0; m < 8; ++m)
#pragma unroll
        for (int i = 0; i < 4; ++i) {
          const int mr = bm + wr * 128 + m * 16 + g * 4 + i;
          const int bb = mr >> 11, s = mr & 2047;
          O[((size_t)(bb * NH + h) * SEQ + s) * HDIM + hd] =
              f2bf((acc[m][n][i] + bv) * jb.scale);
        }
    }
  } else if (jb.mode == 2) {
    unsigned short* O = (unsigned short*)jb.out;
#pragma unroll
    for (int n = 0; n < 4; ++n) {
      const int nc = bn + wc * 64 + n * 16 + r;
      const float bv = jb.bias[nc];
      const int h = nc >> 6, hd = nc & 63;
#pragma unroll
      for (int m = 0; m < 8; ++m) {
        const int mr = bm + wr * 128 + m * 16 + g * 4;   // quad-aligned s
        const int bb = mr >> 11, s = mr & 2047;
        ushort4 pv;
        pv.x = f2bf(acc[m][n][0] + bv);
        pv.y = f2bf(acc[m][n][1] + bv);
        pv.z = f2bf(acc[m][n][2] + bv);
        pv.w = f2bf(acc[m][n][3] + bv);
        *(ushort4*)(O + ((size_t)(bb * NH + h) * HDIM + hd) * SEQ + s) = pv;
      }
    }
  } else {
    float* O = (float*)jb.out;
#pragma unroll
    for (int n = 0; n < 4; ++n) {
      const int nc = bn + wc * 64 + n * 16 + r;
      const float bv = jb.bias[nc];
#pragma unroll
      for (int m = 0; m < 8; ++m)
#pragma unroll
        for (int i = 0; i < 4; ++i) {
          const int mr = bm + wr * 128 + m * 16 + g * 4 + i;
          O[(size_t)mr * DM + nc] = acc[m][n][i] + bv;
        }
    }
  }
}

// ---------------------------------------------------------------- attention
// (unchanged from R5 — frozen to isolate the GEMM delta)
struct AttnJob { const unsigned short* Q; const unsigned short* K;
                 const unsigned short* Vt; unsigned short* O; };
struct AttnJobs { AttnJob j[2]; };

__global__ __launch_bounds__(512, 4)
void k_attn(AttnJobs jobs) {
  const AttnJob jb = jobs.j[blockIdx.z];
  const int nid = blockIdx.x + (blockIdx.y << 3);        // 0..255
  const int qt = nid >> 5;                               // q-tile 0..7
  const int bh = ((nid & 7) << 2) + ((nid >> 3) & 3);    // bh 0..31
  const int lane = threadIdx.x & 63, w = threadIdx.x >> 6;  // w 0..7
  const int q5 = lane & 31, hi = lane >> 5;
  const int qrow = qt * 256 + w * 32 + q5;

  const unsigned short* Qp = jb.Q + (size_t)bh * SEQ * HDIM;
  const unsigned short* Kp = jb.K + (size_t)bh * SEQ * HDIM;
  const unsigned short* Vp = jb.Vt + (size_t)bh * HDIM * SEQ;

  __shared__ __align__(16) unsigned short Ks[3][64 * 64];
  __shared__ __align__(16) unsigned short Vs[3][64 * 64];

  bf16x8 qf[4];
#pragma unroll
  for (int c = 0; c < 4; ++c)
    qf[c] = ld8(Qp + (size_t)qrow * HDIM + c * 16 + hi * 8);

  const int srow = w * 8 + (lane >> 3);
  const int schunk = (lane & 7) ^ (srow & 7);
  const unsigned short* Kg = Kp + (size_t)srow * HDIM + schunk * 8;
  const unsigned short* Vg = Vp + (size_t)srow * SEQ + schunk * 8;

  auto stage = [&](int buf, int kv0) {
    gll16(Kg + (size_t)kv0 * HDIM, Ks[buf] + w * 512);
    gll16(Vg + kv0,                Vs[buf] + w * 512);
  };

  f32x16 o0 = {}, o1 = {};
  float mrow = -1e30f, lrow = 0.f;
  const int swzl = q5 & 7;
  constexpr int NT = SEQ / 64;  // 32

  stage(0, 0);
  stage(1, 64);
  asm volatile("s_waitcnt vmcnt(2)" ::: "memory");
  __builtin_amdgcn_s_barrier();
  __builtin_amdgcn_sched_barrier(0);

  int cur = 0, sb = 2;
  for (int t = 0; t < NT; ++t) {
    if (t + 2 < NT) stage(sb, (t + 2) * 64);

    f32x16 s0 = {}, s1 = {};
    __builtin_amdgcn_s_setprio(1);
#pragma unroll
    for (int c = 0; c < 4; ++c) {
      const int sl = ((2 * c + hi) ^ swzl) * 8;
      s0 = mfma32(ld8(Ks[cur] + q5 * 64 + sl), qf[c], s0);
      s1 = mfma32(ld8(Ks[cur] + (32 + q5) * 64 + sl), qf[c], s1);
    }
    __builtin_amdgcn_s_setprio(0);

    float tm[8];
#pragma unroll
    for (int rr = 0; rr < 8; ++rr)
      tm[rr] = fmaxf(fmaxf(s0[rr], s0[rr + 8]), fmaxf(s1[rr], s1[rr + 8]));
    float mx = fmaxf(fmaxf(fmaxf(tm[0], tm[1]), tm[2]),
                     fmaxf(fmaxf(tm[3], tm[4]), fmaxf(fmaxf(tm[5], tm[6]), tm[7])));
    mx = fmaxf(mx, __shfl_xor(mx, 32, 64));

    if (!__all(mx <= mrow + 11.5416f)) {
      const float mn = fmaxf(mx, mrow);
      const float al = __builtin_amdgcn_exp2f(mrow - mn);
      mrow = mn;
      lrow *= al;
#pragma unroll
      for (int rr = 0; rr < 16; ++rr) { o0[rr] *= al; o1[rr] *= al; }
    }

    float ps0 = 0.f, ps1 = 0.f;
#pragma unroll
    for (int rr = 0; rr < 16; ++rr) {
      s0[rr] = __builtin_amdgcn_exp2f(s0[rr] - mrow); ps0 += s0[rr];
      s1[rr] = __builtin_amdgcn_exp2f(s1[rr] - mrow); ps1 += s1[rr];
    }
    lrow += ps0 + ps1;

    unsigned pk0[8], pk1[8];
#pragma unroll
    for (int ww = 0; ww < 8; ++ww) {
      pk0[ww] = cvtpk(s0[2 * ww], s0[2 * ww + 1]);
      pk1[ww] = cvtpk(s1[2 * ww], s1[2 * ww + 1]);
    }

    __builtin_amdgcn_s_setprio(1);
#pragma unroll
    for (int c = 0; c < 4; ++c) {
      const int wb = 4 * (c & 1);
      unsigned a0 = (c < 2) ? pk0[wb + 0] : pk1[wb + 0];
      unsigned a1 = (c < 2) ? pk0[wb + 1] : pk1[wb + 1];
      unsigned b0 = (c < 2) ? pk0[wb + 2] : pk1[wb + 2];
      unsigned b1 = (c < 2) ? pk0[wb + 3] : pk1[wb + 3];
      plswap(a0, b0);
      plswap(a1, b1);
      uint32x4 fw = {a0, a1, b0, b1};
      const bf16x8 pf = __builtin_bit_cast(bf16x8, fw);
      const int sl = ((2 * c + hi) ^ swzl) * 8;
      o0 = mfma32(ld8(Vs[cur] + q5 * 64 + sl), pf, o0);
      o1 = mfma32(ld8(Vs[cur] + (32 + q5) * 64 + sl), pf, o1);
    }
    __builtin_amdgcn_s_setprio(0);

    if (t + 1 < NT) {
      if (t + 2 < NT) {
        asm volatile("s_waitcnt vmcnt(2)" ::: "memory");
      } else {
        asm volatile("s_waitcnt vmcnt(0)" ::: "memory");
      }
      __builtin_amdgcn_s_barrier();
      __builtin_amdgcn_sched_barrier(0);
    }
    sb = cur;
    cur = (cur == 2) ? 0 : cur + 1;
  }

  const float ltot = lrow + __shfl_xor(lrow, 32, 64);
  const float inv = 1.f / ltot;
  const int bb = bh >> 4, h = bh & 15;
  unsigned short* Ob = jb.O + ((size_t)bb * SEQ + qrow) * DM + h * HDIM;

  auto storeO = [&](const f32x16 oo, int dbase) {
#pragma unroll
    for (int g4 = 0; g4 < 4; ++g4) {
      ushort4 pv;
      pv.x = f2bf(oo[4 * g4 + 0] * inv);
      pv.y = f2bf(oo[4 * g4 + 1] * inv);
      pv.z = f2bf(oo[4 * g4 + 2] * inv);
      pv.w = f2bf(oo[4 * g4 + 3] * inv);
      *(ushort4*)(Ob + dbase + 8 * g4 + 4 * hi) = pv;
    }
  };
  storeO(o0, 0);
  storeO(o1, 32);
}

// ---------------------------------------------------------------- launch
extern "C" void kernel_launch(void* const* d_in, const int* in_sizes, int n_in,
                              void* d_out, int out_size, void* d_ws, size_t ws_size,
                              hipStream_t stream) {
  const float* vis = (const float*)d_in[0];
  const float* inff = (const float*)d_in[1];

  unsigned short* xbf  = (unsigned short*)d_ws;        // [2][4096][1024] bf16
  unsigned short* wt   = xbf + 2 * XSZ;                // 8 x [1024][1024] bf16 (transposed)
  unsigned short* Qv   = wt + (size_t)8 * 1024 * 1024; // each [B*H, S, HD]
  unsigned short* Kv   = Qv + XSZ;
  unsigned short* Vv   = Kv + XSZ;                     // (unused)
  unsigned short* Qi   = Vv + XSZ;
  unsigned short* Ki   = Qi + XSZ;
  unsigned short* Vi   = Ki + XSZ;                     // (unused)
  unsigned short* Vvt  = Vi + XSZ;                     // [B*H, HD, S] written by GEMM mode2
  unsigned short* Vit  = Vvt + XSZ;
  unsigned short* atA  = Vit + XSZ;                    // softmax(Qv Ki^T) Vi, [B,S,D]
  unsigned short* atB  = atA + XSZ;                    // softmax(Qi Kv^T) Vv

  k_convert_x<<<dim3(2048, 1, 2), 256, 0, stream>>>(vis, inff, xbf);

  WPtrs wp;
  wp.w[0] = (const float*)d_in[2];  wp.w[1] = (const float*)d_in[4];
  wp.w[2] = (const float*)d_in[6];  wp.w[3] = (const float*)d_in[8];
  wp.w[4] = (const float*)d_in[10]; wp.w[5] = (const float*)d_in[12];
  wp.w[6] = (const float*)d_in[14]; wp.w[7] = (const float*)d_in[16];
  k_convert_w<<<dim3(16, 16, 8), 256, 0, stream>>>(wp, wt);

  const size_t WSZ = (size_t)1024 * 1024;
  const float qsc = 0.18033688011f;  // log2(e)/8 -> softmax in base-2 domain
  GemmJobs pj;
  pj.j[0] = { xbf,       wt + 0 * WSZ, (const float*)d_in[3],  (void*)Qv,  qsc, 0 };
  pj.j[1] = { xbf,       wt + 1 * WSZ, (const float*)d_in[5],  (void*)Kv,  1.f, 0 };
  pj.j[2] = { xbf,       wt + 2 * WSZ, (const float*)d_in[7],  (void*)Vvt, 1.f, 2 };
  pj.j[3] = { xbf + XSZ, wt + 3 * WSZ, (const float*)d_in[9],  (void*)Qi,  qsc, 0 };
  pj.j[4] = { xbf + XSZ, wt + 4 * WSZ, (const float*)d_in[11], (void*)Ki,  1.f, 0 };
  pj.j[5] = { xbf + XSZ, wt + 5 * WSZ, (const float*)d_in[13], (void*)Vit, 1.f, 2 };
  k_gemm256<<<dim3(4, 16, 6), 512, 0, stream>>>(pj);

  AttnJobs aj;
  aj.j[0] = { Qv, Ki, Vit, atA };  // vis queries over inf K/V -> out_inf path
  aj.j[1] = { Qi, Kv, Vvt, atB };  // inf queries over vis K/V -> out_vis path
  k_attn<<<dim3(8, 32, 2), 512, 0, stream>>>(aj);

  GemmJobs oj;
  oj.j[0] = { atB, wt + 6 * WSZ, (const float*)d_in[15], d_out, 1.f, 1 };                      // out_vis
  oj.j[1] = { atA, wt + 7 * WSZ, (const float*)d_in[17], (void*)((float*)d_out + XSZ), 1.f, 1 }; // out_inf
  for (int z = 2; z < 6; ++z) oj.j[z] = oj.j[0];  // unused slots
  k_gemm256<<<dim3(4, 16, 2), 512, 0, stream>>>(oj);
}